// Round 1
// 1096.890 us; speedup vs baseline: 1.1266x; 1.1266x over previous
//
#include <hip/hip_runtime.h>

// Problem: B=4, DIM=192, H=W=256, HEADS=6, d=32, WS=8 -> 4096 windows x 64 tokens
// One block per window, 256 threads = 4 waves, 3 blocks/CU (LDS 53248 B).
//
// Key layout rule used everywhere:
//   MFMA16(A_frag, B_frag): lane(quad=lane>>4, col=lane&15) holds
//   D[row = <A-row base> + quad*4 + r][col-lane = <B-row base> + col].
// With A = weight rows, B = token rows, the 4 r-values are 4 consecutive
// CHANNELS for one token -> packed 8B LDS stores in token-major buffers.

typedef __attribute__((ext_vector_type(8))) short short8;   // 8 bf16
typedef __attribute__((ext_vector_type(4))) short short4b;  // 4 bf16 (8B)
typedef __attribute__((ext_vector_type(4))) float floatx4;

#define MFMA16(a, b, c) __builtin_amdgcn_mfma_f32_16x16x32_bf16((a), (b), (c), 0, 0, 0)

__device__ __forceinline__ float bf2f(unsigned short u) {
    return __uint_as_float(((unsigned int)u) << 16);
}
__device__ __forceinline__ unsigned short f2bf(float f) {
    unsigned int x = __float_as_uint(f);
    x += 0x7fffu + ((x >> 16) & 1u);
    return (unsigned short)(x >> 16);
}
__device__ __forceinline__ void st_bf4(unsigned short* p, float x0, float x1, float x2, float x3) {
    short4b v;
    v[0] = (short)f2bf(x0); v[1] = (short)f2bf(x1);
    v[2] = (short)f2bf(x2); v[3] = (short)f2bf(x3);
    *(short4b*)p = v;   // single 8B ds_write_b64
}
__device__ __forceinline__ float gelu_exact(float x) {
    return 0.5f * x * (1.0f + erff(x * 0.70710678118654752f));
}

// bf16 transposed-weight layout in workspace (element offsets, shorts):
// qkvT [576][192], bpeT [384][32], projT [192][192], fc1T [768][192], fc2T [192][768]
#define QKVT  0
#define BPET  110592
#define PROJT 122880
#define FC1T  159744
#define FC2T  307200
#define WTOT  454656

__global__ void convert_weights_kernel(
    const float* __restrict__ qkv_w, const float* __restrict__ bpe_w,
    const float* __restrict__ proj_w, const float* __restrict__ fc1_w,
    const float* __restrict__ fc2_w, unsigned short* __restrict__ wt)
{
    int i = blockIdx.x * 256 + threadIdx.x;
    if (i < 110592) { int n = i / 192, k = i % 192; wt[QKVT + i] = f2bf(qkv_w[k * 576 + n]); return; }
    i -= 110592;
    if (i < 12288)  { int n = i / 32,  k = i % 32;  wt[BPET + i] = f2bf(bpe_w[k * 384 + n]); return; }
    i -= 12288;
    if (i < 36864)  { int n = i / 192, k = i % 192; wt[PROJT + i] = f2bf(proj_w[k * 192 + n]); return; }
    i -= 36864;
    if (i < 147456) { int n = i / 192, k = i % 192; wt[FC1T + i] = f2bf(fc1_w[k * 768 + n]); return; }
    i -= 147456;
    if (i < 147456) { int n = i / 768, k = i % 768; wt[FC2T + i] = f2bf(fc2_w[k * 192 + n]); return; }
}

// LDS map (bytes), total 53248 -> 3 blocks/CU:
//  OFF_XN  0      [64][200] bf16 xn (LN1 out, later LN2 out); B4: stg [96][66] f32 (25344)
//  OFF_QC  25600  [64][72] bf16 q|bq (scaled); A2 overwrites in place with P [64][64]
//                 phase-B: hbuf [64][136] bf16 (17408)
//  OFF_KC  34816  [64][72] bf16 k|bk
//  OFF_VT  44032  [32][64] bf16 V^T, XOR-swizzled  (4096)
//  OFF_OB  48128  [64][40] bf16: phase0 bpe staging, then per-head O (token-major)
//  OFF_SR  51200  [64][4] f32 LN2 partial sums (phase B only, aliases tail of OB)
//  OFF_SR2 52224
#define OFF_XN   0
#define OFF_QC   25600
#define OFF_KC   34816
#define OFF_VT   44032
#define OFF_OB   48128
#define OFF_SR   51200
#define OFF_SR2  52224
#define LDS_TOT  53248

#define VTIDX(ch, tok) ((((ch) * 64) + (tok)) ^ (((ch) & 7) << 3))

__global__ __launch_bounds__(256, 3) void fused_mfma_kernel(
    const float* __restrict__ x,      // (4,192,256,256)
    const float* __restrict__ bpe,    // (4,32,256,256)
    const float* __restrict__ ln1_w, const float* __restrict__ ln1_b,
    const float* __restrict__ qkv_b,  // (576)
    const float* __restrict__ bpe_b,  // (384)
    const float* __restrict__ proj_b, // (192)
    const float* __restrict__ ln2_w, const float* __restrict__ ln2_b,
    const float* __restrict__ fc1_b,  // (768)
    const float* __restrict__ fc2_b,  // (192)
    const unsigned short* __restrict__ wt, // bf16 transposed weights
    float* __restrict__ out)          // (4,192,256,256)
{
    __shared__ __align__(16) unsigned char smem[LDS_TOT];
    unsigned short* xn    = (unsigned short*)(smem + OFF_XN);
    unsigned short* qc    = (unsigned short*)(smem + OFF_QC);
    unsigned short* kc    = (unsigned short*)(smem + OFF_KC);
    unsigned short* vt    = (unsigned short*)(smem + OFF_VT);
    unsigned short* ob    = (unsigned short*)(smem + OFF_OB);   // bpe_s, then O
    float*          sred  = (float*)(smem + OFF_SR);
    float*          s2red = (float*)(smem + OFF_SR2);
    unsigned short* hbuf  = (unsigned short*)(smem + OFF_QC);   // phase-B overlay
    float*          stg   = (float*)(smem + OFF_XN);            // phase-B overlay

    const int tid  = threadIdx.x;
    const int lane = tid & 63;
    const int wv   = tid >> 6;
    const int quad = lane >> 4;
    const int col  = lane & 15;

    // XCD-aware swizzle: adjacent windows (sharing 64B x-lines) -> same XCD
    const int orig = blockIdx.x;
    const int wid  = ((orig & 7) << 9) | (orig >> 3);
    const int b   = wid >> 10;
    const int rem = wid & 1023;
    const int h0  = (rem >> 5) << 3;
    const int w0  = (rem & 31) << 3;

    const float SCALE = 0.17677669529663687f; // 1/sqrt(32)

    // ---------------- Phase 0: load + LN1 ----------------
    for (int e = tid; e < 64 * 96; e += 256) {          // x: float2 per thread
        int tp = e & 31, c = e >> 5;
        int t = tp * 2;
        float2 v = *(const float2*)(x + b * (192 * 65536) + c * 65536 +
                                    (h0 + (t >> 3)) * 256 + (w0 + (t & 7)));
        xn[t * 200 + c]       = f2bf(v.x);
        xn[(t + 1) * 200 + c] = f2bf(v.y);
    }
    for (int e = tid; e < 64 * 16; e += 256) {          // bpe -> ob staging
        int tp = e & 31, c = e >> 5;
        int t = tp * 2;
        float2 v = *(const float2*)(bpe + b * (32 * 65536) + c * 65536 +
                                    (h0 + (t >> 3)) * 256 + (w0 + (t & 7)));
        ob[t * 40 + c]       = f2bf(v.x);
        ob[(t + 1) * 40 + c] = f2bf(v.y);
    }
    __syncthreads();

    // hoist bpe fragments to registers (wave 3 only); frees ob for O
    short8 ab[4];
    if (wv == 3) {
        #pragma unroll
        for (int mt = 0; mt < 4; ++mt)
            ab[mt] = *(const short8*)(ob + (mt * 16 + col) * 40 + quad * 8);
    }

    // LN1 (vectorized short8)
    {
        int t = tid >> 2, sub = tid & 3, c0 = sub * 48;
        float s = 0.f, s2 = 0.f;
        #pragma unroll
        for (int j = 0; j < 6; ++j) {
            short8 v8 = *(const short8*)(xn + t * 200 + c0 + j * 8);
            #pragma unroll
            for (int k = 0; k < 8; ++k) {
                float f = bf2f((unsigned short)v8[k]);
                s += f; s2 += f * f;
            }
        }
        s  += __shfl_xor(s, 1);  s  += __shfl_xor(s, 2);
        s2 += __shfl_xor(s2, 1); s2 += __shfl_xor(s2, 2);
        float m    = s * (1.0f / 192.0f);
        float var  = s2 * (1.0f / 192.0f) - m * m;
        float rstd = rsqrtf(var + 1e-5f);
        #pragma unroll
        for (int j = 0; j < 6; ++j) {
            short8 v8 = *(const short8*)(xn + t * 200 + c0 + j * 8);
            floatx4 wa = *(const floatx4*)(ln1_w + c0 + j * 8);
            floatx4 wb = *(const floatx4*)(ln1_w + c0 + j * 8 + 4);
            floatx4 ba = *(const floatx4*)(ln1_b + c0 + j * 8);
            floatx4 bb = *(const floatx4*)(ln1_b + c0 + j * 8 + 4);
            short8 o8;
            #pragma unroll
            for (int k = 0; k < 4; ++k)
                o8[k] = (short)f2bf((bf2f((unsigned short)v8[k]) - m) * rstd * wa[k] + ba[k]);
            #pragma unroll
            for (int k = 0; k < 4; ++k)
                o8[4 + k] = (short)f2bf((bf2f((unsigned short)v8[4 + k]) - m) * rstd * wb[k] + bb[k]);
            *(short8*)(xn + t * 200 + c0 + j * 8) = o8;
        }
    }
    __syncthreads();

    // proj accumulator: D[out-ch = wv*48+nt*16+quad*4+r][tok = mt*16+col]
    floatx4 Cp[3][4];
    #pragma unroll
    for (int nt = 0; nt < 3; ++nt)
        #pragma unroll
        for (int mt = 0; mt < 4; ++mt)
            Cp[nt][mt] = (floatx4){0.f, 0.f, 0.f, 0.f};

    // ---------------- Phase A: per-head attention ----------------
    for (int h = 0; h < 6; ++h) {
        const int h32 = h * 32;

        // ---- A1: wave-specialized q / k / v / bqk GEMMs ----
        if (wv < 2) {
            // wv==0: q (scaled) ; wv==1: k  — SWAPPED: D[ch][tok] -> packed b64
            const int rbase = wv * 192 + h32;
            floatx4 C[2][4];
            #pragma unroll
            for (int nt = 0; nt < 2; ++nt)
                #pragma unroll
                for (int mt = 0; mt < 4; ++mt) C[nt][mt] = (floatx4){0.f,0.f,0.f,0.f};
            #pragma unroll
            for (int ks = 0; ks < 6; ++ks) {
                short8 xb[4];
                #pragma unroll
                for (int mt = 0; mt < 4; ++mt)
                    xb[mt] = *(const short8*)(xn + (mt * 16 + col) * 200 + ks * 32 + quad * 8);
                #pragma unroll
                for (int nt = 0; nt < 2; ++nt) {
                    short8 wf = *(const short8*)(wt + QKVT + (rbase + nt * 16 + col) * 192 + ks * 32 + quad * 8);
                    #pragma unroll
                    for (int mt = 0; mt < 4; ++mt) C[nt][mt] = MFMA16(wf, xb[mt], C[nt][mt]);
                }
            }
            unsigned short* dst = (wv == 0) ? qc : kc;
            const float sc = (wv == 0) ? SCALE : 1.0f;
            #pragma unroll
            for (int nt = 0; nt < 2; ++nt) {
                floatx4 b4 = *(const floatx4*)(qkv_b + rbase + nt * 16 + quad * 4);
                #pragma unroll
                for (int mt = 0; mt < 4; ++mt)
                    st_bf4(dst + (mt * 16 + col) * 72 + nt * 16 + quad * 4,
                           (C[nt][mt][0] + b4[0]) * sc, (C[nt][mt][1] + b4[1]) * sc,
                           (C[nt][mt][2] + b4[2]) * sc, (C[nt][mt][3] + b4[3]) * sc);
            }
        } else if (wv == 2) {
            // v -> V^T (channel-major, swizzled). UNSWAPPED: D[tok][ch],
            // r-values = consecutive tokens -> packed b64 into vt rows.
            const int rbase = 384 + h32;
            floatx4 C[2][4];
            #pragma unroll
            for (int nt = 0; nt < 2; ++nt)
                #pragma unroll
                for (int mt = 0; mt < 4; ++mt) C[nt][mt] = (floatx4){0.f,0.f,0.f,0.f};
            #pragma unroll
            for (int ks = 0; ks < 6; ++ks) {
                short8 xb[4];
                #pragma unroll
                for (int mt = 0; mt < 4; ++mt)
                    xb[mt] = *(const short8*)(xn + (mt * 16 + col) * 200 + ks * 32 + quad * 8);
                #pragma unroll
                for (int nt = 0; nt < 2; ++nt) {
                    short8 wf = *(const short8*)(wt + QKVT + (rbase + nt * 16 + col) * 192 + ks * 32 + quad * 8);
                    #pragma unroll
                    for (int mt = 0; mt < 4; ++mt) C[nt][mt] = MFMA16(xb[mt], wf, C[nt][mt]);
                }
            }
            #pragma unroll
            for (int nt = 0; nt < 2; ++nt) {
                float bias = qkv_b[rbase + nt * 16 + col];
                int ch = nt * 16 + col;
                #pragma unroll
                for (int mt = 0; mt < 4; ++mt)
                    st_bf4(vt + VTIDX(ch, mt * 16 + quad * 4),
                           C[nt][mt][0] + bias, C[nt][mt][1] + bias,
                           C[nt][mt][2] + bias, C[nt][mt][3] + bias);
            }
        } else {
            // wv==3: bq (scaled) -> qc cols 32..63 ; bk -> kc cols 32..63 (SWAPPED)
            floatx4 C[2][2][4];
            #pragma unroll
            for (int qk = 0; qk < 2; ++qk)
                #pragma unroll
                for (int nt = 0; nt < 2; ++nt)
                    #pragma unroll
                    for (int mt = 0; mt < 4; ++mt) C[qk][nt][mt] = (floatx4){0.f,0.f,0.f,0.f};
            #pragma unroll
            for (int qk = 0; qk < 2; ++qk) {
                const int rb2 = qk * 192 + h32;
                #pragma unroll
                for (int nt = 0; nt < 2; ++nt) {
                    short8 wf = *(const short8*)(wt + BPET + (rb2 + nt * 16 + col) * 32 + quad * 8);
                    #pragma unroll
                    for (int mt = 0; mt < 4; ++mt) C[qk][nt][mt] = MFMA16(wf, ab[mt], C[qk][nt][mt]);
                }
            }
            #pragma unroll
            for (int qk = 0; qk < 2; ++qk) {
                unsigned short* dst = qk ? kc : qc;
                const float sc2 = qk ? 1.0f : SCALE;
                #pragma unroll
                for (int nt = 0; nt < 2; ++nt) {
                    floatx4 b4 = *(const floatx4*)(bpe_b + qk * 192 + h32 + nt * 16 + quad * 4);
                    #pragma unroll
                    for (int mt = 0; mt < 4; ++mt)
                        st_bf4(dst + (mt * 16 + col) * 72 + 32 + nt * 16 + quad * 4,
                               (C[qk][nt][mt][0] + b4[0]) * sc2, (C[qk][nt][mt][1] + b4[1]) * sc2,
                               (C[qk][nt][mt][2] + b4[2]) * sc2, (C[qk][nt][mt][3] + b4[3]) * sc2);
                }
            }
        }
        __syncthreads();

        // ---- A2: S^T = K@Q^T, in-lane softmax, P overwrites qc (wave-private rows)
        {
            const int m0 = wv * 16;
            short8 q0 = *(const short8*)(qc + (m0 + col) * 72 + quad * 8);
            short8 q1 = *(const short8*)(qc + (m0 + col) * 72 + 32 + quad * 8);
            floatx4 Cs[4];   // Cs[nt][r] = S[q=m0+col][k=nt*16+quad*4+r]
            #pragma unroll
            for (int nt = 0; nt < 4; ++nt) {
                short8 k0 = *(const short8*)(kc + (nt * 16 + col) * 72 + quad * 8);
                short8 k1 = *(const short8*)(kc + (nt * 16 + col) * 72 + 32 + quad * 8);
                floatx4 z = (floatx4){0.f, 0.f, 0.f, 0.f};
                z = MFMA16(k0, q0, z);
                z = MFMA16(k1, q1, z);
                Cs[nt] = z;
            }
            float mx = Cs[0][0];
            #pragma unroll
            for (int nt = 0; nt < 4; ++nt)
                #pragma unroll
                for (int r = 0; r < 4; ++r) mx = fmaxf(mx, Cs[nt][r]);
            mx = fmaxf(mx, __shfl_xor(mx, 16));
            mx = fmaxf(mx, __shfl_xor(mx, 32));
            float sum = 0.f;
            #pragma unroll
            for (int nt = 0; nt < 4; ++nt)
                #pragma unroll
                for (int r = 0; r < 4; ++r) {
                    float e = __expf(Cs[nt][r] - mx);
                    Cs[nt][r] = e; sum += e;
                }
            sum += __shfl_xor(sum, 16);
            sum += __shfl_xor(sum, 32);
            float inv = 1.0f / sum;
            #pragma unroll
            for (int nt = 0; nt < 4; ++nt)
                st_bf4(qc + (m0 + col) * 72 + nt * 16 + quad * 4,
                       Cs[nt][0] * inv, Cs[nt][1] * inv, Cs[nt][2] * inv, Cs[nt][3] * inv);
        }
        // no barrier: A3 reads only this wave's P rows (in-wave LDS order) + vt (A1-barriered)

        // ---- A3: O^T = V^T@P^T -> token-major Ob, packed b64 ----
        {
            const int m0 = wv * 16;
            short8 p0 = *(const short8*)(qc + (m0 + col) * 72 + quad * 8);
            short8 p1 = *(const short8*)(qc + (m0 + col) * 72 + 32 + quad * 8);
            #pragma unroll
            for (int nt = 0; nt < 2; ++nt) {
                int ch = nt * 16 + col;
                short8 v0 = *(const short8*)(vt + VTIDX(ch, quad * 8));
                short8 v1 = *(const short8*)(vt + VTIDX(ch, 32 + quad * 8));
                floatx4 z = (floatx4){0.f, 0.f, 0.f, 0.f};
                z = MFMA16(v0, p0, z);
                z = MFMA16(v1, p1, z);
                st_bf4(ob + (m0 + col) * 40 + nt * 16 + quad * 4, z[0], z[1], z[2], z[3]);
            }
        }
        __syncthreads();

        // ---- A4: proj accumulation (SWAPPED: D[out-ch][tok]) ----
        {
            short8 ao[4];
            #pragma unroll
            for (int mt = 0; mt < 4; ++mt)
                ao[mt] = *(const short8*)(ob + (mt * 16 + col) * 40 + quad * 8);
            #pragma unroll
            for (int nt = 0; nt < 3; ++nt) {
                short8 wf = *(const short8*)(wt + PROJT + (wv * 48 + nt * 16 + col) * 192 + h32 + quad * 8);
                #pragma unroll
                for (int mt = 0; mt < 4; ++mt) Cp[nt][mt] = MFMA16(wf, ao[mt], Cp[nt][mt]);
            }
        }
        // no barrier before next A1 (disjoint buffers; A1-end barrier gates reuse)
    }
    __syncthreads();   // phase-A exit: ob dead before sred writes (they alias)

    // ---------------- Phase B ----------------
    // B1: xh2 = Cp + proj_b + raw x, residual loaded DIRECTLY to registers (f32-exact).
    float xh2a[3][4][4];
    {
        int toff[4];
        #pragma unroll
        for (int mt = 0; mt < 4; ++mt)
            toff[mt] = (h0 + 2 * mt + (col >> 3)) * 256 + w0 + (col & 7);
        const float* xb = x + b * 12582912 + (wv * 48 + quad * 4) * 65536;
        #pragma unroll
        for (int nt = 0; nt < 3; ++nt) {
            floatx4 pb4 = *(const floatx4*)(proj_b + wv * 48 + nt * 16 + quad * 4);
            #pragma unroll
            for (int mt = 0; mt < 4; ++mt)
                #pragma unroll
                for (int r = 0; r < 4; ++r)
                    xh2a[nt][mt][r] = Cp[nt][mt][r] + pb4[r] + xb[(nt * 16 + r) * 65536 + toff[mt]];
        }
    }

    // B2: LN2 — in-lane 12-ch sums + cross-quad shuffles + cross-wave LDS
    #pragma unroll
    for (int mt = 0; mt < 4; ++mt) {
        float s = 0.f, s2 = 0.f;
        #pragma unroll
        for (int nt = 0; nt < 3; ++nt)
            #pragma unroll
            for (int r = 0; r < 4; ++r) {
                float v = xh2a[nt][mt][r];
                s += v; s2 += v * v;
            }
        s  += __shfl_xor(s, 16);  s  += __shfl_xor(s, 32);
        s2 += __shfl_xor(s2, 16); s2 += __shfl_xor(s2, 32);
        if (quad == 0) {
            sred[(mt * 16 + col) * 4 + wv]  = s;
            s2red[(mt * 16 + col) * 4 + wv] = s2;
        }
    }
    __syncthreads();
    {
        floatx4 lw4[3], lb4[3];
        #pragma unroll
        for (int nt = 0; nt < 3; ++nt) {
            lw4[nt] = *(const floatx4*)(ln2_w + wv * 48 + nt * 16 + quad * 4);
            lb4[nt] = *(const floatx4*)(ln2_b + wv * 48 + nt * 16 + quad * 4);
        }
        #pragma unroll
        for (int mt = 0; mt < 4; ++mt) {
            floatx4 sv  = *(const floatx4*)(sred + (mt * 16 + col) * 4);
            floatx4 s2v = *(const floatx4*)(s2red + (mt * 16 + col) * 4);
            float S  = sv[0] + sv[1] + sv[2] + sv[3];
            float S2 = s2v[0] + s2v[1] + s2v[2] + s2v[3];
            float m    = S * (1.0f / 192.0f);
            float var  = S2 * (1.0f / 192.0f) - m * m;
            float rstd = rsqrtf(var + 1e-5f);
            #pragma unroll
            for (int nt = 0; nt < 3; ++nt)
                st_bf4(xn + (mt * 16 + col) * 200 + wv * 48 + nt * 16 + quad * 4,
                       (xh2a[nt][mt][0] - m) * rstd * lw4[nt][0] + lb4[nt][0],
                       (xh2a[nt][mt][1] - m) * rstd * lw4[nt][1] + lb4[nt][1],
                       (xh2a[nt][mt][2] - m) * rstd * lw4[nt][2] + lb4[nt][2],
                       (xh2a[nt][mt][3] - m) * rstd * lw4[nt][3] + lb4[nt][3]);
        }
    }
    __syncthreads();

    // B3: MLP in 6 chunks of 128 hidden (lower register pressure than 4x192)
    floatx4 Cf[3][4];
    #pragma unroll
    for (int nt = 0; nt < 3; ++nt)
        #pragma unroll
        for (int mt = 0; mt < 4; ++mt) Cf[nt][mt] = (floatx4){0.f, 0.f, 0.f, 0.f};

    for (int cn = 0; cn < 6; ++cn) {
        // fc1 chunk (SWAPPED) + gelu -> hbuf [64][136], packed b64 stores
        {
            floatx4 C1[2][4];
            #pragma unroll
            for (int nt = 0; nt < 2; ++nt)
                #pragma unroll
                for (int mt = 0; mt < 4; ++mt) C1[nt][mt] = (floatx4){0.f, 0.f, 0.f, 0.f};
            #pragma unroll
            for (int ks = 0; ks < 6; ++ks) {
                short8 xb2[4];
                #pragma unroll
                for (int mt = 0; mt < 4; ++mt)
                    xb2[mt] = *(const short8*)(xn + (mt * 16 + col) * 200 + ks * 32 + quad * 8);
                #pragma unroll
                for (int nt = 0; nt < 2; ++nt) {
                    short8 wf = *(const short8*)(wt + FC1T + (cn * 128 + wv * 32 + nt * 16 + col) * 192 + ks * 32 + quad * 8);
                    #pragma unroll
                    for (int mt = 0; mt < 4; ++mt) C1[nt][mt] = MFMA16(wf, xb2[mt], C1[nt][mt]);
                }
            }
            #pragma unroll
            for (int nt = 0; nt < 2; ++nt) {
                floatx4 b4 = *(const floatx4*)(fc1_b + cn * 128 + wv * 32 + nt * 16 + quad * 4);
                #pragma unroll
                for (int mt = 0; mt < 4; ++mt)
                    st_bf4(hbuf + (mt * 16 + col) * 136 + wv * 32 + nt * 16 + quad * 4,
                           gelu_exact(C1[nt][mt][0] + b4[0]), gelu_exact(C1[nt][mt][1] + b4[1]),
                           gelu_exact(C1[nt][mt][2] + b4[2]), gelu_exact(C1[nt][mt][3] + b4[3]));
            }
        }
        __syncthreads();
        // fc2 accumulate over this chunk (SWAPPED, K=128)
        {
            #pragma unroll
            for (int ks = 0; ks < 4; ++ks) {
                short8 hb[4];
                #pragma unroll
                for (int mt = 0; mt < 4; ++mt)
                    hb[mt] = *(const short8*)(hbuf + (mt * 16 + col) * 136 + ks * 32 + quad * 8);
                #pragma unroll
                for (int nt = 0; nt < 3; ++nt) {
                    short8 wf = *(const short8*)(wt + FC2T + (wv * 48 + nt * 16 + col) * 768 +
                                                 cn * 128 + ks * 32 + quad * 8);
                    #pragma unroll
                    for (int mt = 0; mt < 4; ++mt) Cf[nt][mt] = MFMA16(wf, hb[mt], Cf[nt][mt]);
                }
            }
        }
        __syncthreads();
    }

    // B4: out = xh2 + mlp + fc2_b, staged via stg [96 ch][66] f32 in xn region
    floatx4 fb4[3];
    #pragma unroll
    for (int nt = 0; nt < 3; ++nt)
        fb4[nt] = *(const floatx4*)(fc2_b + wv * 48 + nt * 16 + quad * 4);

    // pass 0: channels 0..95 (waves 0,1)
    if (wv < 2) {
        #pragma unroll
        for (int nt = 0; nt < 3; ++nt)
            #pragma unroll
            for (int mt = 0; mt < 4; ++mt)
                #pragma unroll
                for (int r = 0; r < 4; ++r)
                    stg[(wv * 48 + nt * 16 + quad * 4 + r) * 66 + mt * 16 + col] =
                        xh2a[nt][mt][r] + Cf[nt][mt][r] + fb4[nt][r];
    }
    __syncthreads();
    for (int e = tid; e < 64 * 48; e += 256) {
        int tp = e & 31, cl = e >> 5;
        int t = tp * 2;
        float2 v = *(const float2*)(stg + cl * 66 + t);
        *(float2*)(out + ((b * 192 + cl) << 16) + (h0 + (t >> 3)) * 256 + (w0 + (t & 7))) = v;
    }
    __syncthreads();
    // pass 1: channels 96..191 (waves 2,3)
    if (wv >= 2) {
        #pragma unroll
        for (int nt = 0; nt < 3; ++nt)
            #pragma unroll
            for (int mt = 0; mt < 4; ++mt)
                #pragma unroll
                for (int r = 0; r < 4; ++r)
                    stg[((wv - 2) * 48 + nt * 16 + quad * 4 + r) * 66 + mt * 16 + col] =
                        xh2a[nt][mt][r] + Cf[nt][mt][r] + fb4[nt][r];
    }
    __syncthreads();
    for (int e = tid; e < 64 * 48; e += 256) {
        int tp = e & 31, cl = e >> 5;
        int t = tp * 2;
        float2 v = *(const float2*)(stg + cl * 66 + t);
        *(float2*)(out + ((b * 192 + 96 + cl) << 16) + (h0 + (t >> 3)) * 256 + (w0 + (t & 7))) = v;
    }
}

extern "C" void kernel_launch(void* const* d_in, const int* in_sizes, int n_in,
                              void* d_out, int out_size, void* d_ws, size_t ws_size,
                              hipStream_t stream) {
    const float* x      = (const float*)d_in[0];
    const float* bpe    = (const float*)d_in[1];
    const float* ln1_w  = (const float*)d_in[2];
    const float* ln1_b  = (const float*)d_in[3];
    const float* qkv_w  = (const float*)d_in[4];
    const float* qkv_b  = (const float*)d_in[5];
    const float* bpe_w  = (const float*)d_in[6];
    const float* bpe_b  = (const float*)d_in[7];
    const float* proj_w = (const float*)d_in[8];
    const float* proj_b = (const float*)d_in[9];
    const float* ln2_w  = (const float*)d_in[10];
    const float* ln2_b  = (const float*)d_in[11];
    const float* fc1_w  = (const float*)d_in[12];
    const float* fc1_b  = (const float*)d_in[13];
    const float* fc2_w  = (const float*)d_in[14];
    const float* fc2_b  = (const float*)d_in[15];

    unsigned short* wt = (unsigned short*)d_ws; // 909 KB bf16 transposed weights

    convert_weights_kernel<<<(WTOT + 255) / 256, 256, 0, stream>>>(
        qkv_w, bpe_w, proj_w, fc1_w, fc2_w, wt);
    fused_mfma_kernel<<<4096, 256, 0, stream>>>(
        x, bpe, ln1_w, ln1_b, qkv_b, bpe_b, proj_b, ln2_w, ln2_b,
        fc1_b, fc2_b, wt, (float*)d_out);
}